// Round 6
// baseline (325.171 us; speedup 1.0000x reference)
//
#include <hip/hip_runtime.h>
#include <math.h>

// Rod_Block: N=8, C_IN=64, C_OUT=128, G=4, CG=16, K=3, P=9, PAD=1, H=W=64.
// All tensors fp32. Padded spatial 66x66.
// Round-6: k_dwsamp v3 (16 pix/block, LDS-staged weights, b128 LDS reads,
// 4-pixel weight amortization), k_proj v2 (16 pix/block), border-only zero.

// ---- K0: zero only the border of xpad (8*260 border pixels * 64 ch = 133,120) ----
__global__ __launch_bounds__(256) void k_zero_border(float* xpad) {
    int idx = blockIdx.x * 256 + threadIdx.x;   // 520*256 = 133,120
    int c  = idx & 63;
    int t  = idx >> 6;          // 0..2079 = n*260 + bp
    int n  = t / 260;
    int bp = t - n * 260;
    int r, q;
    if (bp < 66)       { r = 0;  q = bp; }
    else if (bp < 132) { r = 65; q = bp - 66; }
    else {
        int s = bp - 132;       // 0..127
        r = 1 + (s >> 1);
        q = (s & 1) ? 65 : 0;
    }
    xpad[((((size_t)n * 66) + r) * 66 + q) * 64 + c] = 0.f;
}

// ---- K1: pooled[n,c] = mean_{h,w} x[n,c,h,w]  (512 blocks x 256) ----
__global__ __launch_bounds__(256) void k_pool(const float* x, float* pooled) {
    __shared__ float red[256];
    int nc = blockIdx.x;
    const float4* p4 = reinterpret_cast<const float4*>(x + (size_t)nc * 4096);
    float s = 0.f;
    for (int i = threadIdx.x; i < 1024; i += 256) {
        float4 v = p4[i];
        s += v.x + v.y + v.z + v.w;
    }
    red[threadIdx.x] = s;
    __syncthreads();
    for (int o = 128; o > 0; o >>= 1) {
        if (threadIdx.x < o) red[threadIdx.x] += red[threadIdx.x + o];
        __syncthreads();
    }
    if (threadIdx.x == 0) pooled[nc] = red[0] * (1.f / 4096.f);
}

// ---- K2: gain1p = 1 + sigmoid(relu(pooled@gw1+gb1)@gw2+gb2)  (1 block x 256) ----
__global__ __launch_bounds__(256) void k_gain(const float* pooled,
                       const float* gw1, const float* gb1,
                       const float* gw2, const float* gb2,
                       float* gain1p) {
    __shared__ float hid[128];
    int tid = threadIdx.x;
    if (tid < 128) {
        int n = tid >> 4, j = tid & 15;
        float s = gb1[j];
        for (int c = 0; c < 64; ++c) s += pooled[n * 64 + c] * gw1[c * 16 + j];
        hid[tid] = fmaxf(s, 0.f);
    }
    __syncthreads();
    for (int t = tid; t < 512; t += 256) {
        int n = t >> 6, c = t & 63;
        float s = gb2[c];
        for (int j = 0; j < 16; ++j) s += hid[n * 16 + j] * gw2[j * 64 + c];
        gain1p[t] = 1.f + 1.f / (1.f + expf(-s));
    }
}

// ---- K3: xs(NHWC) = x*(1+gain) + relu(refl*tap_w+tap_b)  (512 blocks x 256) ----
__global__ __launch_bounds__(256) void k_xs(const float* x, const float* refl,
                     const float* tap_w, const float* tap_b,
                     const float* gain1p, float* xs) {
    __shared__ float tile[64 * 65];
    __shared__ float rrow[64];
    int n = blockIdx.x >> 6, h = blockIdx.x & 63;
    int tid = threadIdx.x;
    for (int i = tid; i < 4096; i += 256) {
        int c = i >> 6, w = i & 63;
        tile[c * 65 + w] = x[(((size_t)(n * 64 + c)) * 64 + h) * 64 + w];
    }
    if (tid < 64) rrow[tid] = refl[n * 4096 + h * 64 + tid];
    __syncthreads();
    for (int i = tid; i < 4096; i += 256) {
        int w = i >> 6, c = i & 63;
        float r = fmaxf(rrow[w] * tap_w[c] + tap_b[c], 0.f);
        xs[(((size_t)(n * 64 + h)) * 64 + w) * 64 + c] =
            tile[c * 65 + w] * gain1p[n * 64 + c] + r;
    }
}

// ---- K4: input_proj into padded interior (2048 blocks x 256, 16 pix/block) ----
__global__ __launch_bounds__(256) void k_proj(const float* xs, const float* inp_w,
                       const float* inp_b, float* xpad) {
    __shared__ float wl[64 * 64];   // [c][co]
    __shared__ float xr[16][64];    // [pix][c]
    int tid = threadIdx.x;
    int base = blockIdx.x * 16;
    for (int i = tid; i < 1024; i += 256)
        *reinterpret_cast<float4*>(&wl[i * 4]) = reinterpret_cast<const float4*>(inp_w)[i];
    for (int i = tid; i < 1024; i += 256) {
        int p = i >> 6, c = i & 63;
        xr[p][c] = xs[(size_t)(base + p) * 64 + c];
    }
    __syncthreads();
    int co = tid & 63, pg = tid >> 6;   // wave pg handles pixels pg*4..pg*4+3
    float acc[4];
    float bco = inp_b[co];
    #pragma unroll
    for (int pi = 0; pi < 4; ++pi) acc[pi] = bco;
    for (int c4 = 0; c4 < 64; c4 += 4) {
        float w0 = wl[(c4 + 0) * 64 + co];
        float w1 = wl[(c4 + 1) * 64 + co];
        float w2 = wl[(c4 + 2) * 64 + co];
        float w3 = wl[(c4 + 3) * 64 + co];
        #pragma unroll
        for (int pi = 0; pi < 4; ++pi) {
            float4 d = *reinterpret_cast<const float4*>(&xr[pg * 4 + pi][c4]);
            acc[pi] += d.x * w0 + d.y * w1 + d.z * w2 + d.w * w3;
        }
    }
    #pragma unroll
    for (int pi = 0; pi < 4; ++pi) {
        int pix = base + pg * 4 + pi;
        int n = pix >> 12, h = (pix >> 6) & 63, w = pix & 63;
        xpad[((((size_t)n * 66) + (h + 1)) * 66 + (w + 1)) * 64 + co] = acc[pi];
    }
}

// ---- K5: fused dw3x3+LN+GELU -> off/mask proj -> softmax -> bilinear -> outproj+BN1+ReLU ----
// 2048 blocks x 256; 16 pixels/block, 4 per wave. lane = channel / output index.
__global__ __launch_bounds__(256) void k_dwsamp(const float* xs, const float* xpad,
                       const float* dw_w, const float* dw_b,
                       const float* ln_g, const float* ln_b,
                       const float* off_w, const float* off_b,
                       const float* mask_w, const float* mask_b,
                       const float* outp_w, const float* outp_b,
                       const float* bn1_g, const float* bn1_b,
                       const float* bn1_m, const float* bn1_v,
                       float* vbuf) {
    __shared__ float Wom[64 * 108 + 64];  // [c][j] j<72: off_w, else mask_w; +64 slack
    __shared__ float dwr[16][64];         // GELU(dw) per pixel
    __shared__ float omo[16][80];         // offsets per pixel: [g][20] (18 used)
    __shared__ float omm[16][48];         // mask logits/softmax: [g][12] (9 used)
    __shared__ float dcnl[16][64];        // sampled dcn per pixel

    int tid = threadIdx.x;
    int lane = tid & 63, wv = tid >> 6;
    int wp = wv * 4;                      // wave's local pixel base
    int base = blockIdx.x * 16;

    // stage combined weight matrix (once per block)
    for (int idx = tid; idx < 6912; idx += 256) {
        int c = idx / 108, j = idx - c * 108;
        Wom[idx] = (j < 72) ? off_w[c * 72 + j] : mask_w[c * 36 + (j - 72)];
    }

    // ---- Phase A: depthwise 3x3 + LN + GELU for this wave's 4 pixels ----
    float dwk[9];
    #pragma unroll
    for (int k = 0; k < 9; ++k) dwk[k] = dw_w[k * 64 + lane];
    float dwbv = dw_b[lane], lngv = ln_g[lane], lnbv = ln_b[lane];
    #pragma unroll
    for (int p = 0; p < 4; ++p) {
        int pix = base + wp + p;
        int n = pix >> 12, h = (pix >> 6) & 63, w = pix & 63;
        float s = dwbv;
        for (int ky = 0; ky < 3; ++ky) {
            int y = h + ky - 1;
            if (y < 0 || y > 63) continue;
            for (int kx = 0; kx < 3; ++kx) {
                int x2 = w + kx - 1;
                if (x2 < 0 || x2 > 63) continue;
                s += xs[(((size_t)(n * 64 + y)) * 64 + x2) * 64 + lane] * dwk[ky * 3 + kx];
            }
        }
        float sum = s, sq = s * s;
        #pragma unroll
        for (int o = 32; o > 0; o >>= 1) {
            sum += __shfl_xor(sum, o, 64);
            sq  += __shfl_xor(sq,  o, 64);
        }
        float mu = sum * (1.f / 64.f);
        float var = sq * (1.f / 64.f) - mu * mu;
        float nrm = (s - mu) * rsqrtf(var + 1e-6f) * lngv + lnbv;
        dwr[wp + p][lane] = 0.5f * nrm * (1.f + erff(nrm * 0.70710678118654752f));
    }
    __syncthreads();

    // ---- Phase B: 108 projections for 4 pixels; lane does j=lane and j2=lane+64 ----
    float a1[4], a2[4];
    {
        float b1v = off_b[lane];
        float b2v = 0.f;
        if (lane < 8)       b2v = off_b[lane + 64];
        else if (lane < 44) b2v = mask_b[lane - 8];
        #pragma unroll
        for (int p = 0; p < 4; ++p) { a1[p] = b1v; a2[p] = b2v; }
    }
    for (int c4 = 0; c4 < 64; c4 += 4) {
        float4 d0 = *reinterpret_cast<const float4*>(&dwr[wp + 0][c4]);
        float4 d1 = *reinterpret_cast<const float4*>(&dwr[wp + 1][c4]);
        float4 d2 = *reinterpret_cast<const float4*>(&dwr[wp + 2][c4]);
        float4 d3 = *reinterpret_cast<const float4*>(&dwr[wp + 3][c4]);
        float dv0[4] = {d0.x, d0.y, d0.z, d0.w};
        float dv1[4] = {d1.x, d1.y, d1.z, d1.w};
        float dv2[4] = {d2.x, d2.y, d2.z, d2.w};
        float dv3[4] = {d3.x, d3.y, d3.z, d3.w};
        #pragma unroll
        for (int k = 0; k < 4; ++k) {
            float wa = Wom[(c4 + k) * 108 + lane];
            float wb = Wom[(c4 + k) * 108 + lane + 64];  // slack-padded; unused for lane>=44
            a1[0] += dv0[k] * wa;  a2[0] += dv0[k] * wb;
            a1[1] += dv1[k] * wa;  a2[1] += dv1[k] * wb;
            a1[2] += dv2[k] * wa;  a2[2] += dv2[k] * wb;
            a1[3] += dv3[k] * wa;  a2[3] += dv3[k] * wb;
        }
    }
    {
        int g1 = lane / 18, i1 = lane - g1 * 18;   // j = lane (< 72 always)
        #pragma unroll
        for (int p = 0; p < 4; ++p) {
            omo[wp + p][g1 * 20 + i1] = a1[p];
            if (lane < 8) {
                omo[wp + p][3 * 20 + (lane + 10)] = a2[p];          // j2 in 64..71
            } else if (lane < 44) {
                int jm = lane - 8;                                   // 0..35
                omm[wp + p][(jm / 9) * 12 + (jm % 9)] = a2[p];
            }
        }
    }
    __syncthreads();

    // ---- softmax over P=9 per (pixel, group): lanes 0..15 handle wave's 4 pixels ----
    if (lane < 16) {
        float* row = &omm[wp + (lane >> 2)][(lane & 3) * 12];
        float m = row[0];
        #pragma unroll
        for (int k = 1; k < 9; ++k) m = fmaxf(m, row[k]);
        float e[9], ssum = 0.f;
        #pragma unroll
        for (int k = 0; k < 9; ++k) { e[k] = expf(row[k] - m); ssum += e[k]; }
        float inv = 1.f / ssum;
        #pragma unroll
        for (int k = 0; k < 9; ++k) row[k] = e[k] * inv;
    }
    __syncthreads();

    // ---- Phase C: bilinear deformable sampling (zeros padding) ----
    {
        int g = lane >> 4;
        #pragma unroll
        for (int p = 0; p < 4; ++p) {
            int pix = base + wp + p;
            int n = pix >> 12, h = (pix >> 6) & 63, w = pix & 63;
            const float* xpn = xpad + (size_t)n * 66 * 66 * 64;
            const float* po = &omo[wp + p][g * 20];
            const float* pm = &omm[wp + p][g * 12];
            float4 o0 = *reinterpret_cast<const float4*>(po);
            float4 o1 = *reinterpret_cast<const float4*>(po + 4);
            float4 o2 = *reinterpret_cast<const float4*>(po + 8);
            float4 o3 = *reinterpret_cast<const float4*>(po + 12);
            float ox16 = po[16], oy17 = po[17];
            float4 m0 = *reinterpret_cast<const float4*>(pm);
            float4 m1 = *reinterpret_cast<const float4*>(pm + 4);
            float mk8 = pm[8];
            float offs[18] = {o0.x, o0.y, o0.z, o0.w, o1.x, o1.y, o1.z, o1.w,
                              o2.x, o2.y, o2.z, o2.w, o3.x, o3.y, o3.z, o3.w,
                              ox16, oy17};
            float mks[9] = {m0.x, m0.y, m0.z, m0.w, m1.x, m1.y, m1.z, m1.w, mk8};
            float acc = 0.f;
            #pragma unroll
            for (int pp = 0; pp < 9; ++pp) {
                float px = (float)(w + (pp / 3)) + offs[pp * 2];
                float py = (float)(h + (pp % 3)) + offs[pp * 2 + 1];
                float x0f = floorf(px), y0f = floorf(py);
                float wx = px - x0f, wy = py - y0f;
                int x0 = (int)x0f, y0 = (int)y0f;
                float v00 = 0.f, v01 = 0.f, v10 = 0.f, v11 = 0.f;
                int yok0 = (y0 >= 0) && (y0 < 66);
                int yok1 = (y0 + 1 >= 0) && (y0 + 1 < 66);
                int xok0 = (x0 >= 0) && (x0 < 66);
                int xok1 = (x0 + 1 >= 0) && (x0 + 1 < 66);
                if (yok0 && xok0) v00 = xpn[((size_t)y0 * 66 + x0) * 64 + lane];
                if (yok0 && xok1) v01 = xpn[((size_t)y0 * 66 + x0 + 1) * 64 + lane];
                if (yok1 && xok0) v10 = xpn[((size_t)(y0 + 1) * 66 + x0) * 64 + lane];
                if (yok1 && xok1) v11 = xpn[((size_t)(y0 + 1) * 66 + x0 + 1) * 64 + lane];
                float bl = v00 * (1.f - wy) * (1.f - wx) + v01 * (1.f - wy) * wx
                         + v10 * wy * (1.f - wx) + v11 * wy * wx;
                acc += mks[pp] * bl;
            }
            dcnl[wp + p][lane] = acc;
        }
    }
    __syncthreads();

    // ---- Phase D: output_proj + BN1 + ReLU for 4 pixels ----
    {
        float s2[4];
        float obv = outp_b[lane];
        #pragma unroll
        for (int p = 0; p < 4; ++p) s2[p] = obv;
        for (int c4 = 0; c4 < 64; c4 += 4) {
            float w0 = outp_w[(c4 + 0) * 64 + lane];
            float w1 = outp_w[(c4 + 1) * 64 + lane];
            float w2 = outp_w[(c4 + 2) * 64 + lane];
            float w3 = outp_w[(c4 + 3) * 64 + lane];
            #pragma unroll
            for (int p = 0; p < 4; ++p) {
                float4 d = *reinterpret_cast<const float4*>(&dcnl[wp + p][c4]);
                s2[p] += d.x * w0 + d.y * w1 + d.z * w2 + d.w * w3;
            }
        }
        float sc = bn1_g[lane] * rsqrtf(bn1_v[lane] + 1e-5f);
        float sh = bn1_b[lane] - sc * bn1_m[lane];
        #pragma unroll
        for (int p = 0; p < 4; ++p) {
            int pix = base + wp + p;
            vbuf[(size_t)pix * 64 + lane] = fmaxf(sc * s2[p] + sh, 0.f);
        }
    }
}

// ---- K6: 1x1 conv 64->128 + BN2 + ReLU, fp32 NCHW out (512 blocks x 256) ----
__global__ __launch_bounds__(256) void k_out(const float* vbuf,
                      const float* conv_w, const float* conv_b,
                      const float* bn2_g, const float* bn2_b,
                      const float* bn2_m, const float* bn2_v,
                      float* out) {
    __shared__ float vl[64 * 68];    // [w][c], pad 68
    __shared__ float cwl[64 * 128];  // [c][d]
    int n = blockIdx.x >> 6, h = blockIdx.x & 63;
    int tid = threadIdx.x;
    const float4* vrow4 = reinterpret_cast<const float4*>(vbuf + ((size_t)(n * 64 + h)) * 4096);
    for (int i = tid; i < 1024; i += 256) {
        int idx = i * 4;
        int w = idx >> 6, c = idx & 63;
        *reinterpret_cast<float4*>(&vl[w * 68 + c]) = vrow4[i];
    }
    for (int i = tid; i < 2048; i += 256)
        *reinterpret_cast<float4*>(&cwl[i * 4]) = reinterpret_cast<const float4*>(conv_w)[i];
    __syncthreads();

    int dgrp = tid & 15, wgrp = tid >> 4;   // thread tile: 4 w x 8 d
    int dbase = dgrp * 8, wbase = wgrp * 4;
    float acc[4][8];
    #pragma unroll
    for (int i = 0; i < 4; ++i)
        #pragma unroll
        for (int j = 0; j < 8; ++j) acc[i][j] = 0.f;

    for (int c = 0; c < 64; ++c) {
        float v0 = vl[(wbase + 0) * 68 + c];
        float v1 = vl[(wbase + 1) * 68 + c];
        float v2 = vl[(wbase + 2) * 68 + c];
        float v3 = vl[(wbase + 3) * 68 + c];
        const float4* c4 = reinterpret_cast<const float4*>(&cwl[c * 128 + dbase]);
        float4 wA = c4[0], wB = c4[1];
        float wt[8] = {wA.x, wA.y, wA.z, wA.w, wB.x, wB.y, wB.z, wB.w};
        #pragma unroll
        for (int j = 0; j < 8; ++j) {
            acc[0][j] += v0 * wt[j];
            acc[1][j] += v1 * wt[j];
            acc[2][j] += v2 * wt[j];
            acc[3][j] += v3 * wt[j];
        }
    }

    #pragma unroll
    for (int j = 0; j < 8; ++j) {
        int d = dbase + j;
        float sc = bn2_g[d] * rsqrtf(bn2_v[d] + 1e-5f);
        float sh = sc * (conv_b[d] - bn2_m[d]) + bn2_b[d];
        float4 r;
        r.x = fmaxf(sc * acc[0][j] + sh, 0.f);
        r.y = fmaxf(sc * acc[1][j] + sh, 0.f);
        r.z = fmaxf(sc * acc[2][j] + sh, 0.f);
        r.w = fmaxf(sc * acc[3][j] + sh, 0.f);
        size_t o = (((size_t)(n * 128 + d)) * 64 + h) * 64 + wbase;
        *reinterpret_cast<float4*>(out + o) = r;
    }
}

extern "C" void kernel_launch(void* const* d_in, const int* in_sizes, int n_in,
                              void* d_out, int out_size, void* d_ws, size_t ws_size,
                              hipStream_t stream) {
    const float* x      = (const float*)d_in[0];
    const float* refl   = (const float*)d_in[1];
    const float* gw1    = (const float*)d_in[2];
    const float* gb1    = (const float*)d_in[3];
    const float* gw2    = (const float*)d_in[4];
    const float* gb2    = (const float*)d_in[5];
    const float* tap_w  = (const float*)d_in[6];
    const float* tap_b  = (const float*)d_in[7];
    const float* dw_w   = (const float*)d_in[8];
    const float* dw_b   = (const float*)d_in[9];
    const float* ln_g   = (const float*)d_in[10];
    const float* ln_b   = (const float*)d_in[11];
    const float* inp_w  = (const float*)d_in[12];
    const float* inp_b  = (const float*)d_in[13];
    const float* off_w  = (const float*)d_in[14];
    const float* off_b  = (const float*)d_in[15];
    const float* mask_w = (const float*)d_in[16];
    const float* mask_b = (const float*)d_in[17];
    const float* outp_w = (const float*)d_in[18];
    const float* outp_b = (const float*)d_in[19];
    const float* conv_w = (const float*)d_in[20];
    const float* conv_b = (const float*)d_in[21];
    const float* bn1_g  = (const float*)d_in[22];
    const float* bn1_b  = (const float*)d_in[23];
    const float* bn1_m  = (const float*)d_in[24];
    const float* bn1_v  = (const float*)d_in[25];
    const float* bn2_g  = (const float*)d_in[26];
    const float* bn2_b  = (const float*)d_in[27];
    const float* bn2_m  = (const float*)d_in[28];
    const float* bn2_v  = (const float*)d_in[29];

    // workspace (floats): 512+512+2,097,152+2,230,272+2,097,152 = 6,425,600 (~25.7 MiB)
    float* ws     = (float*)d_ws;
    float* pooled = ws;                    // 512
    float* gain1p = ws + 512;              // 512
    float* xs     = ws + 1024;             // 2,097,152  (NHWC)
    float* xpad   = xs + 2097152;          // 2,230,272  (8*66*66*64, NHWC padded)
    float* vbuf   = xpad + 2230272;        // 2,097,152  (post BN1+ReLU, NHWC)

    k_zero_border<<<520, 256, 0, stream>>>(xpad);
    k_pool<<<512, 256, 0, stream>>>(x, pooled);
    k_gain<<<1, 256, 0, stream>>>(pooled, gw1, gb1, gw2, gb2, gain1p);
    k_xs<<<512, 256, 0, stream>>>(x, refl, tap_w, tap_b, gain1p, xs);
    k_proj<<<2048, 256, 0, stream>>>(xs, inp_w, inp_b, xpad);
    k_dwsamp<<<2048, 256, 0, stream>>>(xs, xpad, dw_w, dw_b, ln_g, ln_b,
                                       off_w, off_b, mask_w, mask_b,
                                       outp_w, outp_b, bn1_g, bn1_b, bn1_m, bn1_v, vbuf);
    k_out<<<512, 256, 0, stream>>>(vbuf, conv_w, conv_b, bn2_g, bn2_b, bn2_m, bn2_v,
                                   (float*)d_out);
}

// Round 7
// 260.988 us; speedup vs baseline: 1.2459x; 1.2459x over previous
//
#include <hip/hip_runtime.h>
#include <math.h>

// Rod_Block: N=8, C_IN=64, C_OUT=128, G=4, CG=16, K=3, P=9, PAD=1, H=W=64.
// All tensors fp32. Padded spatial 66x66.
// Round-7: k_dwsamp v4 — round-5 skeleton (1 pixel/wave, small LDS, high occ)
// + float2 pointer-stride weight loads (B), hoisted sampling coords (C),
// b128 LDS reads. k_proj/k_out/etc. kept from round-6.

// ---- K0: zero only the border of xpad (8*260 border pixels * 64 ch = 133,120) ----
__global__ __launch_bounds__(256) void k_zero_border(float* xpad) {
    int idx = blockIdx.x * 256 + threadIdx.x;   // 520*256 = 133,120
    int c  = idx & 63;
    int t  = idx >> 6;          // 0..2079 = n*260 + bp
    int n  = t / 260;
    int bp = t - n * 260;
    int r, q;
    if (bp < 66)       { r = 0;  q = bp; }
    else if (bp < 132) { r = 65; q = bp - 66; }
    else {
        int s = bp - 132;       // 0..127
        r = 1 + (s >> 1);
        q = (s & 1) ? 65 : 0;
    }
    xpad[((((size_t)n * 66) + r) * 66 + q) * 64 + c] = 0.f;
}

// ---- K1: pooled[n,c] = mean_{h,w} x[n,c,h,w]  (512 blocks x 256) ----
__global__ __launch_bounds__(256) void k_pool(const float* x, float* pooled) {
    __shared__ float red[256];
    int nc = blockIdx.x;
    const float4* p4 = reinterpret_cast<const float4*>(x + (size_t)nc * 4096);
    float s = 0.f;
    for (int i = threadIdx.x; i < 1024; i += 256) {
        float4 v = p4[i];
        s += v.x + v.y + v.z + v.w;
    }
    red[threadIdx.x] = s;
    __syncthreads();
    for (int o = 128; o > 0; o >>= 1) {
        if (threadIdx.x < o) red[threadIdx.x] += red[threadIdx.x + o];
        __syncthreads();
    }
    if (threadIdx.x == 0) pooled[nc] = red[0] * (1.f / 4096.f);
}

// ---- K2: gain1p = 1 + sigmoid(relu(pooled@gw1+gb1)@gw2+gb2)  (1 block x 256) ----
__global__ __launch_bounds__(256) void k_gain(const float* pooled,
                       const float* gw1, const float* gb1,
                       const float* gw2, const float* gb2,
                       float* gain1p) {
    __shared__ float hid[128];
    int tid = threadIdx.x;
    if (tid < 128) {
        int n = tid >> 4, j = tid & 15;
        float s = gb1[j];
        for (int c = 0; c < 64; ++c) s += pooled[n * 64 + c] * gw1[c * 16 + j];
        hid[tid] = fmaxf(s, 0.f);
    }
    __syncthreads();
    for (int t = tid; t < 512; t += 256) {
        int n = t >> 6, c = t & 63;
        float s = gb2[c];
        for (int j = 0; j < 16; ++j) s += hid[n * 16 + j] * gw2[j * 64 + c];
        gain1p[t] = 1.f + 1.f / (1.f + expf(-s));
    }
}

// ---- K3: xs(NHWC) = x*(1+gain) + relu(refl*tap_w+tap_b)  (512 blocks x 256) ----
__global__ __launch_bounds__(256) void k_xs(const float* x, const float* refl,
                     const float* tap_w, const float* tap_b,
                     const float* gain1p, float* xs) {
    __shared__ float tile[64 * 65];
    __shared__ float rrow[64];
    int n = blockIdx.x >> 6, h = blockIdx.x & 63;
    int tid = threadIdx.x;
    for (int i = tid; i < 4096; i += 256) {
        int c = i >> 6, w = i & 63;
        tile[c * 65 + w] = x[(((size_t)(n * 64 + c)) * 64 + h) * 64 + w];
    }
    if (tid < 64) rrow[tid] = refl[n * 4096 + h * 64 + tid];
    __syncthreads();
    for (int i = tid; i < 4096; i += 256) {
        int w = i >> 6, c = i & 63;
        float r = fmaxf(rrow[w] * tap_w[c] + tap_b[c], 0.f);
        xs[(((size_t)(n * 64 + h)) * 64 + w) * 64 + c] =
            tile[c * 65 + w] * gain1p[n * 64 + c] + r;
    }
}

// ---- K4: input_proj into padded interior (2048 blocks x 256, 16 pix/block) ----
__global__ __launch_bounds__(256) void k_proj(const float* xs, const float* inp_w,
                       const float* inp_b, float* xpad) {
    __shared__ float wl[64 * 64];   // [c][co]
    __shared__ float xr[16][64];    // [pix][c]
    int tid = threadIdx.x;
    int base = blockIdx.x * 16;
    for (int i = tid; i < 1024; i += 256)
        *reinterpret_cast<float4*>(&wl[i * 4]) = reinterpret_cast<const float4*>(inp_w)[i];
    for (int i = tid; i < 1024; i += 256) {
        int p = i >> 6, c = i & 63;
        xr[p][c] = xs[(size_t)(base + p) * 64 + c];
    }
    __syncthreads();
    int co = tid & 63, pg = tid >> 6;   // wave pg handles pixels pg*4..pg*4+3
    float acc[4];
    float bco = inp_b[co];
    #pragma unroll
    for (int pi = 0; pi < 4; ++pi) acc[pi] = bco;
    for (int c4 = 0; c4 < 64; c4 += 4) {
        float w0 = wl[(c4 + 0) * 64 + co];
        float w1 = wl[(c4 + 1) * 64 + co];
        float w2 = wl[(c4 + 2) * 64 + co];
        float w3 = wl[(c4 + 3) * 64 + co];
        #pragma unroll
        for (int pi = 0; pi < 4; ++pi) {
            float4 d = *reinterpret_cast<const float4*>(&xr[pg * 4 + pi][c4]);
            acc[pi] += d.x * w0 + d.y * w1 + d.z * w2 + d.w * w3;
        }
    }
    #pragma unroll
    for (int pi = 0; pi < 4; ++pi) {
        int pix = base + pg * 4 + pi;
        int n = pix >> 12, h = (pix >> 6) & 63, w = pix & 63;
        xpad[((((size_t)n * 66) + (h + 1)) * 66 + (w + 1)) * 64 + co] = acc[pi];
    }
}

// ---- K5: fused dw3x3+LN+GELU -> off/mask proj -> softmax+coords -> bilinear -> outproj+BN1+ReLU
// 8192 blocks x 256; 1 pixel per wave (4/block). lane = channel / output index.
__global__ __launch_bounds__(256) void k_dwsamp(const float* xs, const float* xpad,
                       const float* dw_w, const float* dw_b,
                       const float* ln_g, const float* ln_b,
                       const float* off_w, const float* off_b,
                       const float* mask_w, const float* mask_b,
                       const float* outp_w, const float* outp_b,
                       const float* bn1_g, const float* bn1_b,
                       const float* bn1_m, const float* bn1_v,
                       float* vbuf) {
    __shared__ float  dwr[4][64];    // GELU(LN(dw)) per pixel
    __shared__ float  om[4][112];    // offset (0..71) + mask logits (72..107)
    __shared__ int4   sad[4][36];    // per (g,p): 4 clamped element offsets in xpn
    __shared__ float4 swt[4][36];    // per (g,p): validity*mask-premultiplied weights
    __shared__ float  dcnl[4][64];   // sampled dcn per pixel

    int tid = threadIdx.x;
    int lane = tid & 63, wv = tid >> 6;
    int pix = blockIdx.x * 4 + wv;
    int n = pix >> 12, h = (pix >> 6) & 63, w = pix & 63;

    // ---- Phase A: depthwise 3x3 + LN(wave shuffle) + exact GELU ----
    {
        float s = dw_b[lane];
        for (int ky = 0; ky < 3; ++ky) {
            int y = h + ky - 1;
            if (y < 0 || y > 63) continue;
            for (int kx = 0; kx < 3; ++kx) {
                int x2 = w + kx - 1;
                if (x2 < 0 || x2 > 63) continue;
                s += xs[(((size_t)(n * 64 + y)) * 64 + x2) * 64 + lane]
                     * dw_w[(ky * 3 + kx) * 64 + lane];
            }
        }
        float sum = s, sq = s * s;
        #pragma unroll
        for (int o = 32; o > 0; o >>= 1) {
            sum += __shfl_xor(sum, o, 64);
            sq  += __shfl_xor(sq,  o, 64);
        }
        float mu = sum * (1.f / 64.f);
        float var = sq * (1.f / 64.f) - mu * mu;
        float nrm = (s - mu) * rsqrtf(var + 1e-6f) * ln_g[lane] + ln_b[lane];
        dwr[wv][lane] = 0.5f * nrm * (1.f + erff(nrm * 0.70710678118654752f));
    }
    __syncthreads();

    // ---- Phase B: 108 projections; lane L<54 owns j={2L,2L+1} via ptr+stride float2 ----
    {
        int jb = lane * 2;
        const float* wbase;
        int stride;
        float a0 = 0.f, a1 = 0.f;
        if (lane < 36)      { wbase = off_w + jb;          stride = 72; a0 = off_b[jb];       a1 = off_b[jb + 1]; }
        else if (lane < 54) { wbase = mask_w + (jb - 72);  stride = 36; a0 = mask_b[jb - 72]; a1 = mask_b[jb - 71]; }
        else                { wbase = off_w;               stride = 0; }
        for (int c4 = 0; c4 < 64; c4 += 4) {
            float4 d = *reinterpret_cast<const float4*>(&dwr[wv][c4]);
            float dk[4] = {d.x, d.y, d.z, d.w};
            #pragma unroll
            for (int k = 0; k < 4; ++k) {
                float2 w2 = *reinterpret_cast<const float2*>(wbase);
                wbase += stride;
                a0 += dk[k] * w2.x;
                a1 += dk[k] * w2.y;
            }
        }
        if (lane < 54) {
            om[wv][jb]     = a0;
            om[wv][jb + 1] = a1;
        }
    }
    __syncthreads();

    // ---- Phase B2 (lanes 0..35): inline softmax + sampling coords/weights ----
    if (lane < 36) {
        int g = lane / 9, pp = lane - g * 9;
        // softmax over this group's 9 logits (redundant per lane, cheap)
        float m = om[wv][72 + g * 9];
        #pragma unroll
        for (int k = 1; k < 9; ++k) m = fmaxf(m, om[wv][72 + g * 9 + k]);
        float ssum = 0.f, ek = 0.f;
        #pragma unroll
        for (int k = 0; k < 9; ++k) {
            float e = expf(om[wv][72 + g * 9 + k] - m);
            ssum += e;
            if (k == pp) ek = e;
        }
        float mk = ek / ssum;
        float ox = om[wv][g * 18 + pp * 2];
        float oy = om[wv][g * 18 + pp * 2 + 1];
        float px = (float)(w + (pp / 3)) + ox;   // padded coords; kernel grid w-outer/h-inner
        float py = (float)(h + (pp % 3)) + oy;
        float x0f = floorf(px), y0f = floorf(py);
        float wx = px - x0f, wy = py - y0f;
        int x0 = (int)x0f, y0 = (int)y0f;
        int x1 = x0 + 1, y1 = y0 + 1;
        int xc0 = min(max(x0, 0), 65), xc1 = min(max(x1, 0), 65);
        int yc0 = min(max(y0, 0), 65), yc1 = min(max(y1, 0), 65);
        float vx0 = (x0 >= 0 && x0 < 66) ? 1.f : 0.f;
        float vx1 = (x1 >= 0 && x1 < 66) ? 1.f : 0.f;
        float vy0 = (y0 >= 0 && y0 < 66) ? 1.f : 0.f;
        float vy1 = (y1 >= 0 && y1 < 66) ? 1.f : 0.f;
        float wx0 = (1.f - wx) * vx0, wx1 = wx * vx1;
        float wy0 = (1.f - wy) * vy0, wy1 = wy * vy1;
        swt[wv][lane] = make_float4(mk * wy0 * wx0, mk * wy0 * wx1,
                                    mk * wy1 * wx0, mk * wy1 * wx1);
        sad[wv][lane] = make_int4((yc0 * 66 + xc0) * 64, (yc0 * 66 + xc1) * 64,
                                  (yc1 * 66 + xc0) * 64, (yc1 * 66 + xc1) * 64);
    }
    __syncthreads();

    // ---- Phase C: bilinear deformable sampling, branch-free ----
    {
        int gb = (lane >> 4) * 9;
        const float* xpn = xpad + (size_t)n * 66 * 66 * 64;
        float acc = 0.f;
        #pragma unroll
        for (int pp = 0; pp < 9; ++pp) {
            int4   a = sad[wv][gb + pp];
            float4 c = swt[wv][gb + pp];
            acc += c.x * xpn[a.x + lane] + c.y * xpn[a.y + lane]
                 + c.z * xpn[a.z + lane] + c.w * xpn[a.w + lane];
        }
        dcnl[wv][lane] = acc;
    }
    __syncthreads();

    // ---- Phase D: output_proj + BN1 + ReLU ----
    {
        float s2 = outp_b[lane];
        for (int c4 = 0; c4 < 64; c4 += 4) {
            float4 d = *reinterpret_cast<const float4*>(&dcnl[wv][c4]);
            s2 += d.x * outp_w[(c4 + 0) * 64 + lane]
                + d.y * outp_w[(c4 + 1) * 64 + lane]
                + d.z * outp_w[(c4 + 2) * 64 + lane]
                + d.w * outp_w[(c4 + 3) * 64 + lane];
        }
        float sc = bn1_g[lane] * rsqrtf(bn1_v[lane] + 1e-5f);
        float sh = bn1_b[lane] - sc * bn1_m[lane];
        vbuf[(size_t)pix * 64 + lane] = fmaxf(sc * s2 + sh, 0.f);
    }
}

// ---- K6: 1x1 conv 64->128 + BN2 + ReLU, fp32 NCHW out (512 blocks x 256) ----
__global__ __launch_bounds__(256) void k_out(const float* vbuf,
                      const float* conv_w, const float* conv_b,
                      const float* bn2_g, const float* bn2_b,
                      const float* bn2_m, const float* bn2_v,
                      float* out) {
    __shared__ float vl[64 * 68];    // [w][c], pad 68
    __shared__ float cwl[64 * 128];  // [c][d]
    int n = blockIdx.x >> 6, h = blockIdx.x & 63;
    int tid = threadIdx.x;
    const float4* vrow4 = reinterpret_cast<const float4*>(vbuf + ((size_t)(n * 64 + h)) * 4096);
    for (int i = tid; i < 1024; i += 256) {
        int idx = i * 4;
        int w = idx >> 6, c = idx & 63;
        *reinterpret_cast<float4*>(&vl[w * 68 + c]) = vrow4[i];
    }
    for (int i = tid; i < 2048; i += 256)
        *reinterpret_cast<float4*>(&cwl[i * 4]) = reinterpret_cast<const float4*>(conv_w)[i];
    __syncthreads();

    int dgrp = tid & 15, wgrp = tid >> 4;   // thread tile: 4 w x 8 d
    int dbase = dgrp * 8, wbase = wgrp * 4;
    float acc[4][8];
    #pragma unroll
    for (int i = 0; i < 4; ++i)
        #pragma unroll
        for (int j = 0; j < 8; ++j) acc[i][j] = 0.f;

    for (int c = 0; c < 64; ++c) {
        float v0 = vl[(wbase + 0) * 68 + c];
        float v1 = vl[(wbase + 1) * 68 + c];
        float v2 = vl[(wbase + 2) * 68 + c];
        float v3 = vl[(wbase + 3) * 68 + c];
        const float4* c4 = reinterpret_cast<const float4*>(&cwl[c * 128 + dbase]);
        float4 wA = c4[0], wB = c4[1];
        float wt[8] = {wA.x, wA.y, wA.z, wA.w, wB.x, wB.y, wB.z, wB.w};
        #pragma unroll
        for (int j = 0; j < 8; ++j) {
            acc[0][j] += v0 * wt[j];
            acc[1][j] += v1 * wt[j];
            acc[2][j] += v2 * wt[j];
            acc[3][j] += v3 * wt[j];
        }
    }

    #pragma unroll
    for (int j = 0; j < 8; ++j) {
        int d = dbase + j;
        float sc = bn2_g[d] * rsqrtf(bn2_v[d] + 1e-5f);
        float sh = sc * (conv_b[d] - bn2_m[d]) + bn2_b[d];
        float4 r;
        r.x = fmaxf(sc * acc[0][j] + sh, 0.f);
        r.y = fmaxf(sc * acc[1][j] + sh, 0.f);
        r.z = fmaxf(sc * acc[2][j] + sh, 0.f);
        r.w = fmaxf(sc * acc[3][j] + sh, 0.f);
        size_t o = (((size_t)(n * 128 + d)) * 64 + h) * 64 + wbase;
        *reinterpret_cast<float4*>(out + o) = r;
    }
}

extern "C" void kernel_launch(void* const* d_in, const int* in_sizes, int n_in,
                              void* d_out, int out_size, void* d_ws, size_t ws_size,
                              hipStream_t stream) {
    const float* x      = (const float*)d_in[0];
    const float* refl   = (const float*)d_in[1];
    const float* gw1    = (const float*)d_in[2];
    const float* gb1    = (const float*)d_in[3];
    const float* gw2    = (const float*)d_in[4];
    const float* gb2    = (const float*)d_in[5];
    const float* tap_w  = (const float*)d_in[6];
    const float* tap_b  = (const float*)d_in[7];
    const float* dw_w   = (const float*)d_in[8];
    const float* dw_b   = (const float*)d_in[9];
    const float* ln_g   = (const float*)d_in[10];
    const float* ln_b   = (const float*)d_in[11];
    const float* inp_w  = (const float*)d_in[12];
    const float* inp_b  = (const float*)d_in[13];
    const float* off_w  = (const float*)d_in[14];
    const float* off_b  = (const float*)d_in[15];
    const float* mask_w = (const float*)d_in[16];
    const float* mask_b = (const float*)d_in[17];
    const float* outp_w = (const float*)d_in[18];
    const float* outp_b = (const float*)d_in[19];
    const float* conv_w = (const float*)d_in[20];
    const float* conv_b = (const float*)d_in[21];
    const float* bn1_g  = (const float*)d_in[22];
    const float* bn1_b  = (const float*)d_in[23];
    const float* bn1_m  = (const float*)d_in[24];
    const float* bn1_v  = (const float*)d_in[25];
    const float* bn2_g  = (const float*)d_in[26];
    const float* bn2_b  = (const float*)d_in[27];
    const float* bn2_m  = (const float*)d_in[28];
    const float* bn2_v  = (const float*)d_in[29];

    // workspace (floats): 512+512+2,097,152+2,230,272+2,097,152 = 6,425,600 (~25.7 MiB)
    float* ws     = (float*)d_ws;
    float* pooled = ws;                    // 512
    float* gain1p = ws + 512;              // 512
    float* xs     = ws + 1024;             // 2,097,152  (NHWC)
    float* xpad   = xs + 2097152;          // 2,230,272  (8*66*66*64, NHWC padded)
    float* vbuf   = xpad + 2230272;        // 2,097,152  (post BN1+ReLU, NHWC)

    k_zero_border<<<520, 256, 0, stream>>>(xpad);
    k_pool<<<512, 256, 0, stream>>>(x, pooled);
    k_gain<<<1, 256, 0, stream>>>(pooled, gw1, gb1, gw2, gb2, gain1p);
    k_xs<<<512, 256, 0, stream>>>(x, refl, tap_w, tap_b, gain1p, xs);
    k_proj<<<2048, 256, 0, stream>>>(xs, inp_w, inp_b, xpad);
    k_dwsamp<<<8192, 256, 0, stream>>>(xs, xpad, dw_w, dw_b, ln_g, ln_b,
                                       off_w, off_b, mask_w, mask_b,
                                       outp_w, outp_b, bn1_g, bn1_b, bn1_m, bn1_v, vbuf);
    k_out<<<512, 256, 0, stream>>>(vbuf, conv_w, conv_b, bn2_g, bn2_b, bn2_m, bn2_v,
                                   (float*)d_out);
}

// Round 8
// 223.434 us; speedup vs baseline: 1.4553x; 1.1681x over previous
//
#include <hip/hip_runtime.h>
#include <math.h>

// Rod_Block: N=8, C_IN=64, C_OUT=128, G=4, CG=16, K=3, P=9, PAD=1, H=W=64.
// All tensors fp32. Padded spatial 66x66.
// Round-8: 4-kernel pipeline. k_xsproj fuses gain-MLP + xs + input_proj +
// xpad borders. k_dwsamp v5: 2 pixels/wave (weight loads amortized x2,
// shared dw-conv halo), same high-occupancy skeleton as round 7.

// ---- K1: pooled[n,c] = mean_{h,w} x[n,c,h,w]  (512 blocks x 256) ----
__global__ __launch_bounds__(256) void k_pool(const float* x, float* pooled) {
    __shared__ float red[256];
    int nc = blockIdx.x;
    const float4* p4 = reinterpret_cast<const float4*>(x + (size_t)nc * 4096);
    float s = 0.f;
    for (int i = threadIdx.x; i < 1024; i += 256) {
        float4 v = p4[i];
        s += v.x + v.y + v.z + v.w;
    }
    red[threadIdx.x] = s;
    __syncthreads();
    for (int o = 128; o > 0; o >>= 1) {
        if (threadIdx.x < o) red[threadIdx.x] += red[threadIdx.x + o];
        __syncthreads();
    }
    if (threadIdx.x == 0) pooled[nc] = red[0] * (1.f / 4096.f);
}

// ---- K2: fused gain-MLP + xs(NHWC) + input_proj + xpad borders ----
// 512 blocks x 256; one block per (n,h) row of 64 pixels.
__global__ __launch_bounds__(256) void k_xsproj(
        const float* x, const float* refl,
        const float* tap_w, const float* tap_b,
        const float* pooled,
        const float* gw1, const float* gb1,
        const float* gw2, const float* gb2,
        const float* inp_w, const float* inp_b,
        float* xs, float* xpad) {
    __shared__ float smem[64 * 68];  // phase1: tile[c][w] stride 65; phase3+: xsrow[w][c] stride 68
    __shared__ float wl[64 * 64];    // inp_w [c][co]
    __shared__ float hid[16];
    __shared__ float gain[64];
    __shared__ float rrow[64];
    int nh = blockIdx.x;
    int n = nh >> 6, h = nh & 63;
    int tid = threadIdx.x;

    for (int i = tid; i < 1024; i += 256)
        *reinterpret_cast<float4*>(&wl[i * 4]) = reinterpret_cast<const float4*>(inp_w)[i];
    for (int i = tid; i < 4096; i += 256) {
        int c = i >> 6, w = i & 63;
        smem[c * 65 + w] = x[(((size_t)(n * 64 + c)) * 64 + h) * 64 + w];
    }
    if (tid < 64) rrow[tid] = refl[n * 4096 + h * 64 + tid];
    if (tid >= 64 && tid < 80) {
        int j = tid - 64;
        float s = gb1[j];
        for (int c = 0; c < 64; ++c) s += pooled[n * 64 + c] * gw1[c * 16 + j];
        hid[j] = fmaxf(s, 0.f);
    }
    __syncthreads();

    // phase2: register-stage the transpose; compute gain (tid<64)
    int c = tid & 63;
    int wb = tid >> 6;               // 0..3
    float val[16];
    #pragma unroll
    for (int k = 0; k < 16; ++k) val[k] = smem[c * 65 + (wb + k * 4)];
    if (tid < 64) {
        float s = gb2[tid];
        #pragma unroll
        for (int j = 0; j < 16; ++j) s += hid[j] * gw2[j * 64 + tid];
        gain[tid] = 1.f + 1.f / (1.f + expf(-s));
    }
    __syncthreads();

    // phase3: xs = x*(1+sigmoid) + relu(refl*tapw+tapb); write LDS xsrow + global xs
    {
        float gv = gain[c], tw = tap_w[c], tb = tap_b[c];
        #pragma unroll
        for (int k = 0; k < 16; ++k) {
            int w = wb + k * 4;
            float r = fmaxf(rrow[w] * tw + tb, 0.f);
            float v = val[k] * gv + r;
            smem[w * 68 + c] = v;
            xs[(((size_t)nh) * 64 + w) * 64 + c] = v;
        }
    }
    __syncthreads();

    // phase4: input_proj (LDS weights, broadcast xsrow reads) + xpad borders
    {
        int co = tid & 63, grp = tid >> 6;
        float acc[16];
        float bv = inp_b[co];
        #pragma unroll
        for (int i = 0; i < 16; ++i) acc[i] = bv;
        for (int c4 = 0; c4 < 64; c4 += 4) {
            float w0 = wl[(c4 + 0) * 64 + co];
            float w1 = wl[(c4 + 1) * 64 + co];
            float w2 = wl[(c4 + 2) * 64 + co];
            float w3 = wl[(c4 + 3) * 64 + co];
            #pragma unroll
            for (int i = 0; i < 16; ++i) {
                float4 d = *reinterpret_cast<const float4*>(&smem[(grp * 16 + i) * 68 + c4]);
                acc[i] += d.x * w0 + d.y * w1 + d.z * w2 + d.w * w3;
            }
        }
        const size_t rowb = (((size_t)n * 66) + (h + 1)) * 66;
        #pragma unroll
        for (int i = 0; i < 16; ++i) {
            int w = grp * 16 + i;
            xpad[(rowb + (w + 1)) * 64 + co] = acc[i];
        }
        if (tid < 128) {   // left/right border columns of this row
            int cc = tid & 63;
            int col = (tid >> 6) ? 65 : 0;
            xpad[(rowb + col) * 64 + cc] = 0.f;
        }
        if (h == 0) {      // top border row
            const size_t r0 = ((size_t)n * 66) * 66;
            for (int i = tid; i < 4224; i += 256) {
                int q = i >> 6, cc = i & 63;
                xpad[(r0 + q) * 64 + cc] = 0.f;
            }
        }
        if (h == 63) {     // bottom border row
            const size_t r65 = (((size_t)n * 66) + 65) * 66;
            for (int i = tid; i < 4224; i += 256) {
                int q = i >> 6, cc = i & 63;
                xpad[(r65 + q) * 64 + cc] = 0.f;
            }
        }
    }
}

// ---- K3: fused dw3x3+LN+GELU -> off/mask proj -> softmax+coords -> bilinear -> outproj+BN1+ReLU
// 4096 blocks x 256; 2 pixels per wave (8/block), same (n,h) row within a wave.
__global__ __launch_bounds__(256) void k_dwsamp(const float* xs, const float* xpad,
                       const float* dw_w, const float* dw_b,
                       const float* ln_g, const float* ln_b,
                       const float* off_w, const float* off_b,
                       const float* mask_w, const float* mask_b,
                       const float* outp_w, const float* outp_b,
                       const float* bn1_g, const float* bn1_b,
                       const float* bn1_m, const float* bn1_v,
                       float* vbuf) {
    __shared__ float  dwr[8][64];
    __shared__ float  om[8][112];    // offsets (0..71) + mask logits (72..107)
    __shared__ int4   sad[8][36];    // per (g,p): 4 clamped element offsets
    __shared__ float4 swt[8][36];    // per (g,p): validity*mask premultiplied weights
    __shared__ float  dcnl[8][64];

    int tid = threadIdx.x;
    int lane = tid & 63, wv = tid >> 6;
    int pbase = blockIdx.x * 8 + wv * 2;
    int n = pbase >> 12, h = (pbase >> 6) & 63, w0 = pbase & 63;  // pixels (h,w0),(h,w0+1)

    // ---- Phase A: depthwise 3x3 (shared halo columns) + LN + GELU, 2 pixels ----
    {
        float dwk[9];
        #pragma unroll
        for (int k = 0; k < 9; ++k) dwk[k] = dw_w[k * 64 + lane];
        float s0 = dw_b[lane], s1 = s0;
        for (int ky = 0; ky < 3; ++ky) {
            int y = h + ky - 1;
            if (y < 0 || y > 63) continue;
            const float* xrow = xs + (((size_t)(n * 64 + y)) * 64) * 64;
            float v[4];
            #pragma unroll
            for (int dx = 0; dx < 4; ++dx) {
                int x2 = w0 - 1 + dx;
                v[dx] = (x2 >= 0 && x2 <= 63) ? xrow[x2 * 64 + lane] : 0.f;
            }
            s0 += v[0] * dwk[ky * 3 + 0] + v[1] * dwk[ky * 3 + 1] + v[2] * dwk[ky * 3 + 2];
            s1 += v[1] * dwk[ky * 3 + 0] + v[2] * dwk[ky * 3 + 1] + v[3] * dwk[ky * 3 + 2];
        }
        float lngv = ln_g[lane], lnbv = ln_b[lane];
        float ss[2] = {s0, s1};
        #pragma unroll
        for (int p = 0; p < 2; ++p) {
            float s = ss[p];
            float sum = s, sq = s * s;
            #pragma unroll
            for (int o = 32; o > 0; o >>= 1) {
                sum += __shfl_xor(sum, o, 64);
                sq  += __shfl_xor(sq,  o, 64);
            }
            float mu = sum * (1.f / 64.f);
            float var = sq * (1.f / 64.f) - mu * mu;
            float nrm = (s - mu) * rsqrtf(var + 1e-6f) * lngv + lnbv;
            dwr[wv * 2 + p][lane] = 0.5f * nrm * (1.f + erff(nrm * 0.70710678118654752f));
        }
    }
    __syncthreads();

    // ---- Phase B: 108 projections x 2 pixels; lane L<54 owns j={2L,2L+1} ----
    {
        int jb = lane * 2;
        const float* wptr;
        int stride;
        float b0 = 0.f, b1 = 0.f;
        if (lane < 36)      { wptr = off_w + jb;         stride = 72; b0 = off_b[jb];       b1 = off_b[jb + 1]; }
        else if (lane < 54) { wptr = mask_w + (jb - 72); stride = 36; b0 = mask_b[jb - 72]; b1 = mask_b[jb - 71]; }
        else                { wptr = off_w;              stride = 0; }
        float a00 = b0, a01 = b1, a10 = b0, a11 = b1;
        for (int c4 = 0; c4 < 64; c4 += 4) {
            float4 d0 = *reinterpret_cast<const float4*>(&dwr[wv * 2 + 0][c4]);
            float4 d1 = *reinterpret_cast<const float4*>(&dwr[wv * 2 + 1][c4]);
            float dk0[4] = {d0.x, d0.y, d0.z, d0.w};
            float dk1[4] = {d1.x, d1.y, d1.z, d1.w};
            #pragma unroll
            for (int k = 0; k < 4; ++k) {
                float2 w2 = *reinterpret_cast<const float2*>(wptr);
                wptr += stride;
                a00 += dk0[k] * w2.x;  a01 += dk0[k] * w2.y;
                a10 += dk1[k] * w2.x;  a11 += dk1[k] * w2.y;
            }
        }
        if (lane < 54) {
            om[wv * 2 + 0][jb] = a00;  om[wv * 2 + 0][jb + 1] = a01;
            om[wv * 2 + 1][jb] = a10;  om[wv * 2 + 1][jb + 1] = a11;
        }
    }
    __syncthreads();

    // ---- Phase B2 (lanes 0..35): softmax + sampling coords/weights per pixel ----
    #pragma unroll
    for (int p = 0; p < 2; ++p) {
        if (lane < 36) {
            int li = wv * 2 + p;
            int g = lane / 9, pp = lane - g * 9;
            float m = om[li][72 + g * 9];
            #pragma unroll
            for (int k = 1; k < 9; ++k) m = fmaxf(m, om[li][72 + g * 9 + k]);
            float ssum = 0.f, ek = 0.f;
            #pragma unroll
            for (int k = 0; k < 9; ++k) {
                float e = expf(om[li][72 + g * 9 + k] - m);
                ssum += e;
                if (k == pp) ek = e;
            }
            float mk = ek / ssum;
            float ox = om[li][g * 18 + pp * 2];
            float oy = om[li][g * 18 + pp * 2 + 1];
            float px = (float)((w0 + p) + (pp / 3)) + ox;   // kernel grid w-outer/h-inner
            float py = (float)(h + (pp % 3)) + oy;
            float x0f = floorf(px), y0f = floorf(py);
            float wx = px - x0f, wy = py - y0f;
            int x0 = (int)x0f, y0 = (int)y0f;
            int x1 = x0 + 1, y1 = y0 + 1;
            int xc0 = min(max(x0, 0), 65), xc1 = min(max(x1, 0), 65);
            int yc0 = min(max(y0, 0), 65), yc1 = min(max(y1, 0), 65);
            float vx0 = (x0 >= 0 && x0 < 66) ? 1.f : 0.f;
            float vx1 = (x1 >= 0 && x1 < 66) ? 1.f : 0.f;
            float vy0 = (y0 >= 0 && y0 < 66) ? 1.f : 0.f;
            float vy1 = (y1 >= 0 && y1 < 66) ? 1.f : 0.f;
            float wx0 = (1.f - wx) * vx0, wx1 = wx * vx1;
            float wy0 = (1.f - wy) * vy0, wy1 = wy * vy1;
            swt[li][lane] = make_float4(mk * wy0 * wx0, mk * wy0 * wx1,
                                        mk * wy1 * wx0, mk * wy1 * wx1);
            sad[li][lane] = make_int4((yc0 * 66 + xc0) * 64, (yc0 * 66 + xc1) * 64,
                                      (yc1 * 66 + xc0) * 64, (yc1 * 66 + xc1) * 64);
        }
    }
    __syncthreads();

    // ---- Phase C: bilinear deformable sampling, branch-free ----
    {
        int gb = (lane >> 4) * 9;
        const float* xpn = xpad + (size_t)n * 66 * 66 * 64;
        #pragma unroll
        for (int p = 0; p < 2; ++p) {
            int li = wv * 2 + p;
            float acc = 0.f;
            #pragma unroll
            for (int pp = 0; pp < 9; ++pp) {
                int4   a  = sad[li][gb + pp];
                float4 cw = swt[li][gb + pp];
                acc += cw.x * xpn[a.x + lane] + cw.y * xpn[a.y + lane]
                     + cw.z * xpn[a.z + lane] + cw.w * xpn[a.w + lane];
            }
            dcnl[li][lane] = acc;
        }
    }
    __syncthreads();

    // ---- Phase D: output_proj + BN1 + ReLU, 2 pixels ----
    {
        float ob = outp_b[lane];
        float s0 = ob, s1 = ob;
        for (int c4 = 0; c4 < 64; c4 += 4) {
            float w0v = outp_w[(c4 + 0) * 64 + lane];
            float w1v = outp_w[(c4 + 1) * 64 + lane];
            float w2v = outp_w[(c4 + 2) * 64 + lane];
            float w3v = outp_w[(c4 + 3) * 64 + lane];
            float4 d0 = *reinterpret_cast<const float4*>(&dcnl[wv * 2 + 0][c4]);
            float4 d1 = *reinterpret_cast<const float4*>(&dcnl[wv * 2 + 1][c4]);
            s0 += d0.x * w0v + d0.y * w1v + d0.z * w2v + d0.w * w3v;
            s1 += d1.x * w0v + d1.y * w1v + d1.z * w2v + d1.w * w3v;
        }
        float sc = bn1_g[lane] * rsqrtf(bn1_v[lane] + 1e-5f);
        float sh = bn1_b[lane] - sc * bn1_m[lane];
        vbuf[(size_t)(pbase + 0) * 64 + lane] = fmaxf(sc * s0 + sh, 0.f);
        vbuf[(size_t)(pbase + 1) * 64 + lane] = fmaxf(sc * s1 + sh, 0.f);
    }
}

// ---- K4: 1x1 conv 64->128 + BN2 + ReLU, fp32 NCHW out (512 blocks x 256) ----
__global__ __launch_bounds__(256) void k_out(const float* vbuf,
                      const float* conv_w, const float* conv_b,
                      const float* bn2_g, const float* bn2_b,
                      const float* bn2_m, const float* bn2_v,
                      float* out) {
    __shared__ float vl[64 * 68];    // [w][c], pad 68
    __shared__ float cwl[64 * 128];  // [c][d]
    int n = blockIdx.x >> 6, h = blockIdx.x & 63;
    int tid = threadIdx.x;
    const float4* vrow4 = reinterpret_cast<const float4*>(vbuf + ((size_t)(n * 64 + h)) * 4096);
    for (int i = tid; i < 1024; i += 256) {
        int idx = i * 4;
        int w = idx >> 6, c = idx & 63;
        *reinterpret_cast<float4*>(&vl[w * 68 + c]) = vrow4[i];
    }
    for (int i = tid; i < 2048; i += 256)
        *reinterpret_cast<float4*>(&cwl[i * 4]) = reinterpret_cast<const float4*>(conv_w)[i];
    __syncthreads();

    int dgrp = tid & 15, wgrp = tid >> 4;   // thread tile: 4 w x 8 d
    int dbase = dgrp * 8, wbase = wgrp * 4;
    float acc[4][8];
    #pragma unroll
    for (int i = 0; i < 4; ++i)
        #pragma unroll
        for (int j = 0; j < 8; ++j) acc[i][j] = 0.f;

    for (int c = 0; c < 64; ++c) {
        float v0 = vl[(wbase + 0) * 68 + c];
        float v1 = vl[(wbase + 1) * 68 + c];
        float v2 = vl[(wbase + 2) * 68 + c];
        float v3 = vl[(wbase + 3) * 68 + c];
        const float4* c4 = reinterpret_cast<const float4*>(&cwl[c * 128 + dbase]);
        float4 wA = c4[0], wB = c4[1];
        float wt[8] = {wA.x, wA.y, wA.z, wA.w, wB.x, wB.y, wB.z, wB.w};
        #pragma unroll
        for (int j = 0; j < 8; ++j) {
            acc[0][j] += v0 * wt[j];
            acc[1][j] += v1 * wt[j];
            acc[2][j] += v2 * wt[j];
            acc[3][j] += v3 * wt[j];
        }
    }

    #pragma unroll
    for (int j = 0; j < 8; ++j) {
        int d = dbase + j;
        float sc = bn2_g[d] * rsqrtf(bn2_v[d] + 1e-5f);
        float sh = sc * (conv_b[d] - bn2_m[d]) + bn2_b[d];
        float4 r;
        r.x = fmaxf(sc * acc[0][j] + sh, 0.f);
        r.y = fmaxf(sc * acc[1][j] + sh, 0.f);
        r.z = fmaxf(sc * acc[2][j] + sh, 0.f);
        r.w = fmaxf(sc * acc[3][j] + sh, 0.f);
        size_t o = (((size_t)(n * 128 + d)) * 64 + h) * 64 + wbase;
        *reinterpret_cast<float4*>(out + o) = r;
    }
}

extern "C" void kernel_launch(void* const* d_in, const int* in_sizes, int n_in,
                              void* d_out, int out_size, void* d_ws, size_t ws_size,
                              hipStream_t stream) {
    const float* x      = (const float*)d_in[0];
    const float* refl   = (const float*)d_in[1];
    const float* gw1    = (const float*)d_in[2];
    const float* gb1    = (const float*)d_in[3];
    const float* gw2    = (const float*)d_in[4];
    const float* gb2    = (const float*)d_in[5];
    const float* tap_w  = (const float*)d_in[6];
    const float* tap_b  = (const float*)d_in[7];
    const float* dw_w   = (const float*)d_in[8];
    const float* dw_b   = (const float*)d_in[9];
    const float* ln_g   = (const float*)d_in[10];
    const float* ln_b   = (const float*)d_in[11];
    const float* inp_w  = (const float*)d_in[12];
    const float* inp_b  = (const float*)d_in[13];
    const float* off_w  = (const float*)d_in[14];
    const float* off_b  = (const float*)d_in[15];
    const float* mask_w = (const float*)d_in[16];
    const float* mask_b = (const float*)d_in[17];
    const float* outp_w = (const float*)d_in[18];
    const float* outp_b = (const float*)d_in[19];
    const float* conv_w = (const float*)d_in[20];
    const float* conv_b = (const float*)d_in[21];
    const float* bn1_g  = (const float*)d_in[22];
    const float* bn1_b  = (const float*)d_in[23];
    const float* bn1_m  = (const float*)d_in[24];
    const float* bn1_v  = (const float*)d_in[25];
    const float* bn2_g  = (const float*)d_in[26];
    const float* bn2_b  = (const float*)d_in[27];
    const float* bn2_m  = (const float*)d_in[28];
    const float* bn2_v  = (const float*)d_in[29];

    // workspace (floats): 512 + 2,097,152 + 2,230,272 + 2,097,152 ≈ 25.7 MiB
    float* ws     = (float*)d_ws;
    float* pooled = ws;                    // 512
    float* xs     = ws + 512;              // 2,097,152  (NHWC)
    float* xpad   = xs + 2097152;          // 2,230,272  (8*66*66*64, NHWC padded)
    float* vbuf   = xpad + 2230272;        // 2,097,152  (post BN1+ReLU, NHWC)

    k_pool<<<512, 256, 0, stream>>>(x, pooled);
    k_xsproj<<<512, 256, 0, stream>>>(x, refl, tap_w, tap_b, pooled,
                                      gw1, gb1, gw2, gb2, inp_w, inp_b, xs, xpad);
    k_dwsamp<<<4096, 256, 0, stream>>>(xs, xpad, dw_w, dw_b, ln_g, ln_b,
                                       off_w, off_b, mask_w, mask_b,
                                       outp_w, outp_b, bn1_g, bn1_b, bn1_m, bn1_v, vbuf);
    k_out<<<512, 256, 0, stream>>>(vbuf, conv_w, conv_b, bn2_g, bn2_b, bn2_m, bn2_v,
                                   (float*)d_out);
}